// Round 2
// baseline (1379.587 us; speedup 1.0000x reference)
//
#include <hip/hip_runtime.h>

#define N_NODES 50000
#define N_EDGES 800000
#define DIM     256
#define BN_EPS  1e-5f

// ---------------- CSR build (once per launch, reused for 3 layers) ----------

__global__ void k_deg_count(const int* __restrict__ dst, int* __restrict__ degi) {
    int e = blockIdx.x * blockDim.x + threadIdx.x;
    if (e < N_EDGES) atomicAdd(&degi[dst[e]], 1);
}

// Single-block chunked Hillis-Steele scan: csr_off[i] = exclusive prefix of deg.
// Also emits inv_deg = 1/max(deg,1). One-time cost per launch; latency-bound.
__global__ void k_scan(const int* __restrict__ degi, int* __restrict__ off,
                       float* __restrict__ inv_deg) {
    __shared__ int buf[1024];
    __shared__ int carry_s;
    if (threadIdx.x == 0) { carry_s = 0; off[0] = 0; }
    __syncthreads();
    for (int base = 0; base < N_NODES; base += 1024) {
        int i = base + threadIdx.x;
        int v = (i < N_NODES) ? degi[i] : 0;
        if (i < N_NODES) inv_deg[i] = 1.0f / (float)max(v, 1);
        buf[threadIdx.x] = v;
        __syncthreads();
        for (int s = 1; s < 1024; s <<= 1) {
            int t = (threadIdx.x >= s) ? buf[threadIdx.x - s] : 0;
            __syncthreads();
            buf[threadIdx.x] += t;
            __syncthreads();
        }
        int inc = buf[threadIdx.x] + carry_s;
        if (i < N_NODES) off[i + 1] = inc;
        __syncthreads();
        if (threadIdx.x == 1023) carry_s = inc;
        __syncthreads();
    }
}

__global__ void k_fill(const int* __restrict__ src, const int* __restrict__ dst,
                       const int* __restrict__ off, int* __restrict__ cursor,
                       int* __restrict__ csr_src) {
    int e = blockIdx.x * blockDim.x + threadIdx.x;
    if (e < N_EDGES) {
        int d = dst[e];
        int pos = atomicAdd(&cursor[d], 1);
        csr_src[off[d] + pos] = src[e];
    }
}

// ---------------- mean aggregation: one wave per node ----------------------

__global__ void k_aggregate(const float* __restrict__ x, const int* __restrict__ off,
                            const int* __restrict__ csr_src,
                            const float* __restrict__ inv_deg,
                            float* __restrict__ agg) {
    int node = (int)((blockIdx.x * blockDim.x + threadIdx.x) >> 6);
    int lane = threadIdx.x & 63;
    if (node >= N_NODES) return;
    int beg = off[node], end = off[node + 1];
    float4 acc = make_float4(0.f, 0.f, 0.f, 0.f);
    for (int e = beg; e < end; ++e) {
        int s = csr_src[e];
        float4 v = ((const float4*)(x + (size_t)s * DIM))[lane];
        acc.x += v.x; acc.y += v.y; acc.z += v.z; acc.w += v.w;
    }
    float inv = inv_deg[node];
    acc.x *= inv; acc.y *= inv; acc.z *= inv; acc.w *= inv;
    ((float4*)(agg + (size_t)node * DIM))[lane] = acc;
}

// ---------------- fused GEMM: H = agg@Wl + x@Wr + bl -----------------------
// Logical K = 512: first 256 from (agg, Wl), last 256 from (x, Wr).

#define BM 128
#define BN 128
#define BK 16
#define LDA (BM + 4)
#define LDB (BN + 4)

__global__ __launch_bounds__(256) void k_gemm(
        const float* __restrict__ Aagg, const float* __restrict__ Ax,
        const float* __restrict__ Wl, const float* __restrict__ Wr,
        const float* __restrict__ bias, float* __restrict__ H) {
    __shared__ float Asub[BK][LDA];   // transposed: [k][m]
    __shared__ float Bsub[BK][LDB];   // [k][n]
    int tid = threadIdx.x;
    int tx = tid & 15;    // output col group (8 cols each)
    int ty = tid >> 4;    // output row group (8 rows each)
    int brow = blockIdx.x * BM;
    int bcol = blockIdx.y * BN;

    float acc[8][8];
    #pragma unroll
    for (int i = 0; i < 8; ++i)
        #pragma unroll
        for (int j = 0; j < 8; ++j) acc[i][j] = 0.f;

    for (int kt = 0; kt < 512 / BK; ++kt) {
        int k0 = kt * BK;
        const float* Aptr; const float* Bptr; int koff;
        if (k0 < 256) { Aptr = Aagg; Bptr = Wl; koff = k0; }
        else          { Aptr = Ax;   Bptr = Wr; koff = k0 - 256; }

        // A tile: 128 rows x 16 k -> store transposed [k][m]
        #pragma unroll
        for (int q = 0; q < 2; ++q) {
            int idx = tid * 2 + q;          // 0..511
            int row = idx >> 2;             // 0..127
            int c4  = idx & 3;              // which float4 of the 16 k's
            int grow = brow + row;
            float4 v = make_float4(0.f, 0.f, 0.f, 0.f);
            if (grow < N_NODES)
                v = *(const float4*)(Aptr + (size_t)grow * DIM + koff + c4 * 4);
            Asub[c4 * 4 + 0][row] = v.x;
            Asub[c4 * 4 + 1][row] = v.y;
            Asub[c4 * 4 + 2][row] = v.z;
            Asub[c4 * 4 + 3][row] = v.w;
        }
        // B tile: 16 k x 128 cols
        #pragma unroll
        for (int q = 0; q < 2; ++q) {
            int idx = tid * 2 + q;
            int r  = idx >> 5;              // 0..15
            int c4 = idx & 31;              // 0..31
            float4 v = *(const float4*)(Bptr + (size_t)(koff + r) * DIM + bcol + c4 * 4);
            *(float4*)(&Bsub[r][c4 * 4]) = v;
        }
        __syncthreads();

        #pragma unroll
        for (int k = 0; k < BK; ++k) {
            float a[8], b[8];
            *(float4*)&a[0] = *(const float4*)&Asub[k][ty * 8];
            *(float4*)&a[4] = *(const float4*)&Asub[k][ty * 8 + 4];
            *(float4*)&b[0] = *(const float4*)&Bsub[k][tx * 8];
            *(float4*)&b[4] = *(const float4*)&Bsub[k][tx * 8 + 4];
            #pragma unroll
            for (int i = 0; i < 8; ++i)
                #pragma unroll
                for (int j = 0; j < 8; ++j)
                    acc[i][j] = fmaf(a[i], b[j], acc[i][j]);
        }
        __syncthreads();
    }

    float bsv[8];
    *(float4*)&bsv[0] = *(const float4*)(bias + bcol + tx * 8);
    *(float4*)&bsv[4] = *(const float4*)(bias + bcol + tx * 8 + 4);
    #pragma unroll
    for (int i = 0; i < 8; ++i) {
        int grow = brow + ty * 8 + i;
        if (grow < N_NODES) {
            float out[8];
            #pragma unroll
            for (int j = 0; j < 8; ++j) out[j] = acc[i][j] + bsv[j];
            *(float4*)(H + (size_t)grow * DIM + bcol + tx * 8)     = *(float4*)&out[0];
            *(float4*)(H + (size_t)grow * DIM + bcol + tx * 8 + 4) = *(float4*)&out[4];
        }
    }
}

// ---------------- BatchNorm stats + normalize ------------------------------

__global__ void k_stats(const float* __restrict__ H, float* __restrict__ ssum,
                        float* __restrict__ ssq) {
    int col = threadIdx.x;  // 256 threads = DIM
    int nchunks = gridDim.x;
    int rows_per = (N_NODES + nchunks - 1) / nchunks;
    int r0 = blockIdx.x * rows_per;
    int r1 = min(r0 + rows_per, N_NODES);
    float s = 0.f, s2 = 0.f;
    for (int r = r0; r < r1; ++r) {
        float v = H[(size_t)r * DIM + col];
        s += v;
        s2 = fmaf(v, v, s2);
    }
    atomicAdd(&ssum[col], s);
    atomicAdd(&ssq[col], s2);
}

__global__ void k_finalize(const float* __restrict__ ssum, const float* __restrict__ ssq,
                           const float* __restrict__ gamma, const float* __restrict__ beta,
                           float* __restrict__ scale, float* __restrict__ shift) {
    int c = threadIdx.x;
    float mu  = ssum[c] * (1.0f / N_NODES);
    float var = ssq[c] * (1.0f / N_NODES) - mu * mu;
    float rstd = rsqrtf(var + BN_EPS);
    float sc = rstd * gamma[c];
    scale[c] = sc;
    shift[c] = beta[c] - mu * sc;
}

__global__ void k_norm_relu(const float* __restrict__ H, const float* __restrict__ scale,
                            const float* __restrict__ shift, float* __restrict__ Xout) {
    __shared__ float sc[DIM], sh[DIM];
    sc[threadIdx.x] = scale[threadIdx.x];
    sh[threadIdx.x] = shift[threadIdx.x];
    __syncthreads();
    size_t total4 = (size_t)N_NODES * DIM / 4;
    for (size_t i = (size_t)blockIdx.x * blockDim.x + threadIdx.x; i < total4;
         i += (size_t)gridDim.x * blockDim.x) {
        float4 v = ((const float4*)H)[i];
        int c = (int)((i * 4) & (DIM - 1));
        float4 o;
        o.x = fmaxf(fmaf(v.x, sc[c + 0], sh[c + 0]), 0.f);
        o.y = fmaxf(fmaf(v.y, sc[c + 1], sh[c + 1]), 0.f);
        o.z = fmaxf(fmaf(v.z, sc[c + 2], sh[c + 2]), 0.f);
        o.w = fmaxf(fmaf(v.w, sc[c + 3], sh[c + 3]), 0.f);
        ((float4*)Xout)[i] = o;
    }
}

// ---------------- launch ----------------------------------------------------

extern "C" void kernel_launch(void* const* d_in, const int* in_sizes, int n_in,
                              void* d_out, int out_size, void* d_ws, size_t ws_size,
                              hipStream_t stream) {
    const float* x0    = (const float*)d_in[0];
    const float* Wl    = (const float*)d_in[1];
    const float* bl    = (const float*)d_in[2];
    const float* Wr    = (const float*)d_in[3];
    const float* gamma = (const float*)d_in[4];
    const float* beta  = (const float*)d_in[5];
    const int*   ei    = (const int*)d_in[6];
    const int* e_src = ei;
    const int* e_dst = ei + N_EDGES;

    char* ws = (char*)d_ws;
    size_t off = 0;
    auto alloc = [&](size_t bytes) { char* p = ws + off; off = (off + bytes + 255) & ~(size_t)255; return p; };
    float* agg     = (float*)alloc((size_t)N_NODES * DIM * 4);
    float* xbuf    = (float*)alloc((size_t)N_NODES * DIM * 4);
    int*   csr_src = (int*)alloc((size_t)N_EDGES * 4);
    int*   csr_off = (int*)alloc((size_t)(N_NODES + 1) * 4);
    int*   degi    = (int*)alloc((size_t)N_NODES * 4);
    int*   cursor  = (int*)alloc((size_t)N_NODES * 4);
    float* inv_deg = (float*)alloc((size_t)N_NODES * 4);
    float* ssum    = (float*)alloc(DIM * 4 * 2);   // ssum | ssq contiguous
    float* ssq     = ssum + DIM;
    float* scale   = (float*)alloc(DIM * 4);
    float* shift   = (float*)alloc(DIM * 4);

    hipMemsetAsync(degi, 0, (size_t)N_NODES * 4, stream);
    hipMemsetAsync(cursor, 0, (size_t)N_NODES * 4, stream);

    int eb = (N_EDGES + 255) / 256;
    k_deg_count<<<eb, 256, 0, stream>>>(e_dst, degi);
    k_scan<<<1, 1024, 0, stream>>>(degi, csr_off, inv_deg);
    k_fill<<<eb, 256, 0, stream>>>(e_src, e_dst, csr_off, cursor, csr_src);

    float* H = (float*)d_out;
    const float* xin = x0;
    for (int l = 0; l < 3; ++l) {
        k_aggregate<<<(N_NODES + 3) / 4, 256, 0, stream>>>(xin, csr_off, csr_src, inv_deg, agg);
        k_gemm<<<dim3((N_NODES + BM - 1) / BM, DIM / BN), 256, 0, stream>>>(
            agg, xin, Wl + (size_t)l * DIM * DIM, Wr + (size_t)l * DIM * DIM,
            bl + (size_t)l * DIM, H);
        hipMemsetAsync(ssum, 0, DIM * 4 * 2, stream);
        k_stats<<<512, 256, 0, stream>>>(H, ssum, ssq);
        k_finalize<<<1, 256, 0, stream>>>(ssum, ssq, gamma + (size_t)l * DIM,
                                          beta + (size_t)l * DIM, scale, shift);
        float* xo = (l == 2) ? (float*)d_out : xbuf;
        k_norm_relu<<<2048, 256, 0, stream>>>(H, scale, shift, xo);
        xin = xo;
    }
}

// Round 3
// 839.356 us; speedup vs baseline: 1.6436x; 1.6436x over previous
//
#include <hip/hip_runtime.h>

#define N_NODES 50000
#define N_PAD   50176   // 392*128, covers GEMM tile over-read
#define N_EDGES 800000
#define DIM     256
#define KDIM    512     // concat [agg | x]
#define BN_EPS  1e-5f

typedef __attribute__((ext_vector_type(8))) short short8;
typedef __attribute__((ext_vector_type(4))) float floatx4;

__device__ __forceinline__ float bf2f(unsigned short u) {
    return __uint_as_float(((unsigned int)u) << 16);
}
__device__ __forceinline__ unsigned short f2bf(float f) {
    unsigned int b = __float_as_uint(f);
    b = (b + 0x7FFF + ((b >> 16) & 1)) >> 16;   // RNE
    return (unsigned short)b;
}

__device__ __forceinline__ void gload_lds16(const void* g, void* l) {
    __builtin_amdgcn_global_load_lds(
        (const __attribute__((address_space(1))) unsigned int*)g,
        (__attribute__((address_space(3))) unsigned int*)l, 16, 0, 0);
}

// ---------------- CSR build (once per launch) -------------------------------

__global__ void k_deg_count(const int* __restrict__ dst, int* __restrict__ degi) {
    int e = blockIdx.x * blockDim.x + threadIdx.x;
    if (e < N_EDGES) atomicAdd(&degi[dst[e]], 1);
}

__global__ void k_scan(const int* __restrict__ degi, int* __restrict__ off,
                       float* __restrict__ inv_deg) {
    __shared__ int buf[1024];
    __shared__ int carry_s;
    if (threadIdx.x == 0) { carry_s = 0; off[0] = 0; }
    __syncthreads();
    for (int base = 0; base < N_NODES; base += 1024) {
        int i = base + threadIdx.x;
        int v = (i < N_NODES) ? degi[i] : 0;
        if (i < N_NODES) inv_deg[i] = 1.0f / (float)max(v, 1);
        buf[threadIdx.x] = v;
        __syncthreads();
        for (int s = 1; s < 1024; s <<= 1) {
            int t = (threadIdx.x >= s) ? buf[threadIdx.x - s] : 0;
            __syncthreads();
            buf[threadIdx.x] += t;
            __syncthreads();
        }
        int inc = buf[threadIdx.x] + carry_s;
        if (i < N_NODES) off[i + 1] = inc;
        __syncthreads();
        if (threadIdx.x == 1023) carry_s = inc;
        __syncthreads();
    }
}

__global__ void k_fill(const int* __restrict__ src, const int* __restrict__ dst,
                       const int* __restrict__ off, int* __restrict__ cursor,
                       int* __restrict__ csr_src) {
    int e = blockIdx.x * blockDim.x + threadIdx.x;
    if (e < N_EDGES) {
        int d = dst[e];
        int pos = atomicAdd(&cursor[d], 1);
        csr_src[off[d] + pos] = src[e];
    }
}

// ---------------- weight prep: Wcat_t[l][n][k] bf16 (transposed concat) -----

__global__ void k_prep_w(const float* __restrict__ Wl, const float* __restrict__ Wr,
                         unsigned short* __restrict__ Wcat) {
    int gid = blockIdx.x * blockDim.x + threadIdx.x;   // 3*256*512
    if (gid >= 3 * DIM * KDIM) return;
    int k = gid & (KDIM - 1);
    int n = (gid >> 9) & (DIM - 1);
    int l = gid >> 17;
    float v = (k < DIM) ? Wl[(size_t)l * DIM * DIM + (size_t)k * DIM + n]
                        : Wr[(size_t)l * DIM * DIM + (size_t)(k - DIM) * DIM + n];
    Wcat[gid] = f2bf(v);
}

// ---------------- x0 -> bf16 into Acat cols 256..511 ------------------------

__global__ void k_x2bf(const float* __restrict__ x, unsigned short* __restrict__ Acat) {
    size_t i = (size_t)blockIdx.x * blockDim.x + threadIdx.x;  // float4 units
    if (i >= (size_t)N_NODES * (DIM / 4)) return;
    int node = (int)(i >> 6);
    int c = ((int)i & 63) * 4;
    float4 v = ((const float4*)x)[i];
    ushort4 o; o.x = f2bf(v.x); o.y = f2bf(v.y); o.z = f2bf(v.z); o.w = f2bf(v.w);
    *(ushort4*)&Acat[(size_t)node * KDIM + DIM + c] = o;
}

// ---------------- mean aggregation: one wave per node, bf16 in/out ----------

__global__ void k_aggregate(const unsigned short* __restrict__ Acat_x,
                            const int* __restrict__ off,
                            const int* __restrict__ csr_src,
                            const float* __restrict__ inv_deg,
                            unsigned short* __restrict__ Acat_agg) {
    int node = (int)((blockIdx.x * blockDim.x + threadIdx.x) >> 6);
    int lane = threadIdx.x & 63;
    if (node >= N_NODES) return;
    int beg = off[node], end = off[node + 1];
    float ax = 0.f, ay = 0.f, az = 0.f, aw = 0.f;
    for (int e = beg; e < end; ++e) {
        int s = csr_src[e];
        ushort4 u = *(const ushort4*)&Acat_x[(size_t)s * KDIM + DIM + lane * 4];
        ax += bf2f(u.x); ay += bf2f(u.y); az += bf2f(u.z); aw += bf2f(u.w);
    }
    float inv = inv_deg[node];
    ushort4 o;
    o.x = f2bf(ax * inv); o.y = f2bf(ay * inv); o.z = f2bf(az * inv); o.w = f2bf(aw * inv);
    *(ushort4*)&Acat_agg[(size_t)node * KDIM + lane * 4] = o;
}

// ---------------- bf16 MFMA GEMM: H = Acat @ Wcat_t^T + bias ----------------
// A: [N_PAD][512] bf16 row-major. B^T (=Wcat_t): [256][512] bf16 row-major.
// 128x128 tile, 4 waves (2x2), each wave 64x64 = 4x4 frags of 16x16, BK=32.
// LDS layout swizzled: row r (64B) holds its four 16B k-slots permuted by
// slot_stored = (k16 + (r>>1)) & 3  -> 2-way banks max (free).

__global__ __launch_bounds__(256) void k_gemm_mfma(
        const unsigned short* __restrict__ A,
        const unsigned short* __restrict__ Bt,
        const float* __restrict__ bias, float* __restrict__ H) {
    __shared__ __align__(16) short Alds[128 * 32];   // 8 KB
    __shared__ __align__(16) short Blds[128 * 32];   // 8 KB
    int tid = threadIdx.x;
    int wid = tid >> 6;
    int lane = tid & 63;
    int wm = wid >> 1, wn = wid & 1;
    int brow = blockIdx.x * 128;
    int bcol = blockIdx.y * 128;

    floatx4 acc[4][4];
    #pragma unroll
    for (int i = 0; i < 4; ++i)
        #pragma unroll
        for (int j = 0; j < 4; ++j) acc[i][j] = (floatx4){0.f, 0.f, 0.f, 0.f};

    // staging geometry: chunk c = 16 rows; lane covers row c*16+(lane>>2), slot lane&3.
    int st_r0 = (lane >> 2);          // row within chunk
    int st_s  = lane & 3;             // stored slot
    int rb = lane & 15;               // frag row
    int k16r = lane >> 4;             // frag k-slot (8 bf16)

    for (int kt = 0; kt < KDIM / 32; ++kt) {
        int k0 = kt * 32;
        #pragma unroll
        for (int q = 0; q < 2; ++q) {
            int c = wid * 2 + q;
            int r = c * 16 + st_r0;
            int k16 = (st_s - (r >> 1)) & 3;   // inverse swizzle on global source
            gload_lds16(A + (size_t)(brow + r) * KDIM + k0 + k16 * 8, &Alds[c * 512]);
            gload_lds16(Bt + (size_t)(bcol + r) * KDIM + k0 + k16 * 8, &Blds[c * 512]);
        }
        __syncthreads();   // drains vmcnt+lgkmcnt before barrier

        short8 af[4], bfr[4];
        #pragma unroll
        for (int i = 0; i < 4; ++i) {
            int ra = wm * 64 + i * 16 + rb;
            int sa = (k16r + (ra >> 1)) & 3;
            af[i] = *(const short8*)&Alds[ra * 32 + sa * 8];
            int rc = wn * 64 + i * 16 + rb;
            int sc = (k16r + (rc >> 1)) & 3;
            bfr[i] = *(const short8*)&Blds[rc * 32 + sc * 8];
        }
        #pragma unroll
        for (int i = 0; i < 4; ++i)
            #pragma unroll
            for (int j = 0; j < 4; ++j)
                acc[i][j] = __builtin_amdgcn_mfma_f32_16x16x32_bf16(
                    af[i], bfr[j], acc[i][j], 0, 0, 0);
        __syncthreads();
    }

    int rg = lane >> 4;
    #pragma unroll
    for (int j = 0; j < 4; ++j) {
        int col = bcol + wn * 64 + j * 16 + rb;
        float bv = bias[col];
        #pragma unroll
        for (int i = 0; i < 4; ++i) {
            #pragma unroll
            for (int q = 0; q < 4; ++q) {
                int row = brow + wm * 64 + i * 16 + rg * 4 + q;
                if (row < N_NODES)
                    H[(size_t)row * DIM + col] = acc[i][j][q] + bv;
            }
        }
    }
}

// ---------------- BatchNorm stats + normalize ------------------------------

__global__ void k_stats(const float* __restrict__ H, float* __restrict__ ssum,
                        float* __restrict__ ssq) {
    int col = threadIdx.x;
    int nchunks = gridDim.x;
    int rows_per = (N_NODES + nchunks - 1) / nchunks;
    int r0 = blockIdx.x * rows_per;
    int r1 = min(r0 + rows_per, N_NODES);
    float s = 0.f, s2 = 0.f;
    for (int r = r0; r < r1; ++r) {
        float v = H[(size_t)r * DIM + col];
        s += v;
        s2 = fmaf(v, v, s2);
    }
    atomicAdd(&ssum[col], s);
    atomicAdd(&ssq[col], s2);
}

__global__ void k_finalize(const float* __restrict__ ssum, const float* __restrict__ ssq,
                           const float* __restrict__ gamma, const float* __restrict__ beta,
                           float* __restrict__ scale, float* __restrict__ shift) {
    int c = threadIdx.x;
    float mu  = ssum[c] * (1.0f / N_NODES);
    float var = ssq[c] * (1.0f / N_NODES) - mu * mu;
    float rstd = rsqrtf(var + BN_EPS);
    float sc = rstd * gamma[c];
    scale[c] = sc;
    shift[c] = beta[c] - mu * sc;
}

// last=0: write bf16 x into Acat cols 256..511 (next layer). last=1: fp32 out.
__global__ void k_norm_relu(const float* __restrict__ H, const float* __restrict__ scale,
                            const float* __restrict__ shift, float* __restrict__ outF,
                            unsigned short* __restrict__ Acat, int last) {
    __shared__ float sc[DIM], sh[DIM];
    sc[threadIdx.x] = scale[threadIdx.x];
    sh[threadIdx.x] = shift[threadIdx.x];
    __syncthreads();
    size_t total4 = (size_t)N_NODES * DIM / 4;
    for (size_t i = (size_t)blockIdx.x * blockDim.x + threadIdx.x; i < total4;
         i += (size_t)gridDim.x * blockDim.x) {
        float4 v = ((const float4*)H)[i];
        int c = (int)((i * 4) & (DIM - 1));
        float4 o;
        o.x = fmaxf(fmaf(v.x, sc[c + 0], sh[c + 0]), 0.f);
        o.y = fmaxf(fmaf(v.y, sc[c + 1], sh[c + 1]), 0.f);
        o.z = fmaxf(fmaf(v.z, sc[c + 2], sh[c + 2]), 0.f);
        o.w = fmaxf(fmaf(v.w, sc[c + 3], sh[c + 3]), 0.f);
        if (last) {
            ((float4*)outF)[i] = o;
        } else {
            int node = (int)(i >> 6);
            ushort4 u; u.x = f2bf(o.x); u.y = f2bf(o.y); u.z = f2bf(o.z); u.w = f2bf(o.w);
            *(ushort4*)&Acat[(size_t)node * KDIM + DIM + c] = u;
        }
    }
}

// ---------------- launch ----------------------------------------------------

extern "C" void kernel_launch(void* const* d_in, const int* in_sizes, int n_in,
                              void* d_out, int out_size, void* d_ws, size_t ws_size,
                              hipStream_t stream) {
    const float* x0    = (const float*)d_in[0];
    const float* Wl    = (const float*)d_in[1];
    const float* bl    = (const float*)d_in[2];
    const float* Wr    = (const float*)d_in[3];
    const float* gamma = (const float*)d_in[4];
    const float* beta  = (const float*)d_in[5];
    const int*   ei    = (const int*)d_in[6];
    const int* e_src = ei;
    const int* e_dst = ei + N_EDGES;

    char* ws = (char*)d_ws;
    size_t off = 0;
    auto alloc = [&](size_t bytes) { char* p = ws + off; off = (off + bytes + 255) & ~(size_t)255; return p; };
    unsigned short* Acat = (unsigned short*)alloc((size_t)N_PAD * KDIM * 2);  // 51.4 MB
    unsigned short* Wcat = (unsigned short*)alloc((size_t)3 * DIM * KDIM * 2);
    int*   csr_src = (int*)alloc((size_t)N_EDGES * 4);
    int*   csr_off = (int*)alloc((size_t)(N_NODES + 1) * 4);
    int*   degi    = (int*)alloc((size_t)N_NODES * 4);
    int*   cursor  = (int*)alloc((size_t)N_NODES * 4);
    float* inv_deg = (float*)alloc((size_t)N_NODES * 4);
    float* ssum    = (float*)alloc(DIM * 4 * 2);
    float* ssq     = ssum + DIM;
    float* scale   = (float*)alloc(DIM * 4);
    float* shift   = (float*)alloc(DIM * 4);

    hipMemsetAsync(degi, 0, (size_t)N_NODES * 4, stream);
    hipMemsetAsync(cursor, 0, (size_t)N_NODES * 4, stream);

    int eb = (N_EDGES + 255) / 256;
    k_deg_count<<<eb, 256, 0, stream>>>(e_dst, degi);
    k_scan<<<1, 1024, 0, stream>>>(degi, csr_off, inv_deg);
    k_fill<<<eb, 256, 0, stream>>>(e_src, e_dst, csr_off, cursor, csr_src);
    k_prep_w<<<(3 * DIM * KDIM + 255) / 256, 256, 0, stream>>>(Wl, Wr, Wcat);
    k_x2bf<<<(N_NODES * (DIM / 4) + 255) / 256, 256, 0, stream>>>(x0, Acat);

    float* H = (float*)d_out;
    for (int l = 0; l < 3; ++l) {
        k_aggregate<<<(N_NODES + 3) / 4, 256, 0, stream>>>(Acat, csr_off, csr_src, inv_deg, Acat);
        k_gemm_mfma<<<dim3((N_NODES + 127) / 128, DIM / 128), 256, 0, stream>>>(
            Acat, Wcat + (size_t)l * DIM * KDIM, bl + (size_t)l * DIM, H);
        hipMemsetAsync(ssum, 0, DIM * 4 * 2, stream);
        k_stats<<<512, 256, 0, stream>>>(H, ssum, ssq);
        k_finalize<<<1, 256, 0, stream>>>(ssum, ssq, gamma + (size_t)l * DIM,
                                          beta + (size_t)l * DIM, scale, shift);
        k_norm_relu<<<2048, 256, 0, stream>>>(H, scale, shift, H, Acat, (l == 2) ? 1 : 0);
    }
}

// Round 5
// 687.612 us; speedup vs baseline: 2.0063x; 1.2207x over previous
//
#include <hip/hip_runtime.h>

#define N_NODES 50000
#define N_PAD   50176   // 392*128, covers GEMM tile over-read
#define N_EDGES 800000
#define DIM     256
#define KDIM    512     // concat [agg | x]
#define BN_EPS  1e-5f
#define SCAN_NB ((N_NODES + 1023) / 1024)   // 49

typedef __attribute__((ext_vector_type(8))) short short8;
typedef __attribute__((ext_vector_type(4))) float floatx4;

__device__ __forceinline__ float bf2f(unsigned short u) {
    return __uint_as_float(((unsigned int)u) << 16);
}
__device__ __forceinline__ unsigned short f2bf(float f) {
    unsigned int b = __float_as_uint(f);
    b = (b + 0x7FFF + ((b >> 16) & 1)) >> 16;   // RNE
    return (unsigned short)b;
}

__device__ __forceinline__ void gload_lds16(const void* g, void* l) {
    __builtin_amdgcn_global_load_lds(
        (const __attribute__((address_space(1))) unsigned int*)g,
        (__attribute__((address_space(3))) unsigned int*)l, 16, 0, 0);
}

// ---------------- CSR build (once per launch) -------------------------------

__global__ void k_deg_count(const int* __restrict__ dst, int* __restrict__ degi) {
    int e = blockIdx.x * blockDim.x + threadIdx.x;
    if (e < N_EDGES) atomicAdd(&degi[dst[e]], 1);
}

// Hierarchical scan: per-block inclusive scan + block sums.
__global__ void k_scan1(const int* __restrict__ degi, int* __restrict__ off,
                        float* __restrict__ inv_deg, int* __restrict__ bsums) {
    __shared__ int buf[1024];
    int i = blockIdx.x * 1024 + threadIdx.x;
    int v = (i < N_NODES) ? degi[i] : 0;
    if (i < N_NODES) inv_deg[i] = 1.0f / (float)max(v, 1);
    buf[threadIdx.x] = v;
    __syncthreads();
    for (int s = 1; s < 1024; s <<= 1) {
        int t = (threadIdx.x >= s) ? buf[threadIdx.x - s] : 0;
        __syncthreads();
        buf[threadIdx.x] += t;
        __syncthreads();
    }
    if (i < N_NODES) off[i + 1] = buf[threadIdx.x];   // local inclusive
    if (threadIdx.x == 1023) bsums[blockIdx.x] = buf[1023];
    if (i == 0) off[0] = 0;
}

// One wave scans the 49 block sums -> exclusive offsets, in place.
__global__ void k_scan2(int* __restrict__ bsums) {
    int t = threadIdx.x;   // 64 threads
    int orig = (t < SCAN_NB) ? bsums[t] : 0;
    int v = orig;
    for (int s = 1; s < 64; s <<= 1) {
        int u = __shfl_up(v, s, 64);
        if (t >= s) v += u;
    }
    if (t < SCAN_NB) bsums[t] = v - orig;   // exclusive
}

__global__ void k_scan3(int* __restrict__ off, const int* __restrict__ bsums) {
    int i = blockIdx.x * 1024 + threadIdx.x;
    if (i < N_NODES) off[i + 1] += bsums[blockIdx.x];
}

__global__ void k_fill(const int* __restrict__ src, const int* __restrict__ dst,
                       const int* __restrict__ off, int* __restrict__ cursor,
                       int* __restrict__ csr_src) {
    int e = blockIdx.x * blockDim.x + threadIdx.x;
    if (e < N_EDGES) {
        int d = dst[e];
        int pos = atomicAdd(&cursor[d], 1);
        csr_src[off[d] + pos] = src[e];
    }
}

// ---------------- weight prep: Wcat_t[l][n][k] bf16 (transposed concat) -----

__global__ void k_prep_w(const float* __restrict__ Wl, const float* __restrict__ Wr,
                         unsigned short* __restrict__ Wcat) {
    int gid = blockIdx.x * blockDim.x + threadIdx.x;   // 3*256*512
    if (gid >= 3 * DIM * KDIM) return;
    int k = gid & (KDIM - 1);
    int n = (gid >> 9) & (DIM - 1);
    int l = gid >> 17;
    float v = (k < DIM) ? Wl[(size_t)l * DIM * DIM + (size_t)k * DIM + n]
                        : Wr[(size_t)l * DIM * DIM + (size_t)(k - DIM) * DIM + n];
    Wcat[gid] = f2bf(v);
}

// ---------------- x0 -> bf16 into Acat cols 256..511 ------------------------

__global__ void k_x2bf(const float* __restrict__ x, unsigned short* __restrict__ Acat) {
    size_t i = (size_t)blockIdx.x * blockDim.x + threadIdx.x;  // float4 units
    if (i >= (size_t)N_NODES * (DIM / 4)) return;
    int node = (int)(i >> 6);
    int c = ((int)i & 63) * 4;
    float4 v = ((const float4*)x)[i];
    ushort4 o; o.x = f2bf(v.x); o.y = f2bf(v.y); o.z = f2bf(v.z); o.w = f2bf(v.w);
    *(ushort4*)&Acat[(size_t)node * KDIM + DIM + c] = o;
}

// ---------------- mean aggregation: one wave per node, bf16 in/out ----------

__global__ void k_aggregate(const unsigned short* __restrict__ Acat_x,
                            const int* __restrict__ off,
                            const int* __restrict__ csr_src,
                            const float* __restrict__ inv_deg,
                            unsigned short* __restrict__ Acat_agg) {
    int node = (int)((blockIdx.x * blockDim.x + threadIdx.x) >> 6);
    int lane = threadIdx.x & 63;
    if (node >= N_NODES) return;
    int beg = off[node], end = off[node + 1];
    float ax = 0.f, ay = 0.f, az = 0.f, aw = 0.f;
    for (int e = beg; e < end; ++e) {
        int s = csr_src[e];
        ushort4 u = *(const ushort4*)&Acat_x[(size_t)s * KDIM + DIM + lane * 4];
        ax += bf2f(u.x); ay += bf2f(u.y); az += bf2f(u.z); aw += bf2f(u.w);
    }
    float inv = inv_deg[node];
    ushort4 o;
    o.x = f2bf(ax * inv); o.y = f2bf(ay * inv); o.z = f2bf(az * inv); o.w = f2bf(aw * inv);
    *(ushort4*)&Acat_agg[(size_t)node * KDIM + lane * 4] = o;
}

// ---------------- bf16 MFMA GEMM: H(bf16) = Acat @ Wcat_t^T + bias ----------
// Fused BN-stats: per-column sum/sumsq accumulated via shfl-reduce + atomics.

__global__ __launch_bounds__(256) void k_gemm_mfma(
        const unsigned short* __restrict__ A,
        const unsigned short* __restrict__ Bt,
        const float* __restrict__ bias, unsigned short* __restrict__ H,
        float* __restrict__ ssum, float* __restrict__ ssq) {
    __shared__ __align__(16) short Alds[128 * 32];   // 8 KB
    __shared__ __align__(16) short Blds[128 * 32];   // 8 KB
    int tid = threadIdx.x;
    int wid = tid >> 6;
    int lane = tid & 63;
    int wm = wid >> 1, wn = wid & 1;
    int brow = blockIdx.x * 128;
    int bcol = blockIdx.y * 128;

    floatx4 acc[4][4];
    #pragma unroll
    for (int i = 0; i < 4; ++i)
        #pragma unroll
        for (int j = 0; j < 4; ++j) acc[i][j] = (floatx4){0.f, 0.f, 0.f, 0.f};

    int st_r0 = (lane >> 2);          // row within 16-row chunk
    int st_s  = lane & 3;             // stored 16B slot
    int rb = lane & 15;               // frag row/col within 16
    int k16r = lane >> 4;             // frag k-slot (8 bf16)

    for (int kt = 0; kt < KDIM / 32; ++kt) {
        int k0 = kt * 32;
        #pragma unroll
        for (int q = 0; q < 2; ++q) {
            int c = wid * 2 + q;
            int r = c * 16 + st_r0;
            int k16 = (st_s - (r >> 1)) & 3;   // inverse swizzle on global source
            gload_lds16(A + (size_t)(brow + r) * KDIM + k0 + k16 * 8, &Alds[c * 512]);
            gload_lds16(Bt + (size_t)(bcol + r) * KDIM + k0 + k16 * 8, &Blds[c * 512]);
        }
        __syncthreads();

        short8 af[4], bfr[4];
        #pragma unroll
        for (int i = 0; i < 4; ++i) {
            int ra = wm * 64 + i * 16 + rb;
            int sa = (k16r + (ra >> 1)) & 3;
            af[i] = *(const short8*)&Alds[ra * 32 + sa * 8];
            int rc = wn * 64 + i * 16 + rb;
            int sc = (k16r + (rc >> 1)) & 3;
            bfr[i] = *(const short8*)&Blds[rc * 32 + sc * 8];
        }
        #pragma unroll
        for (int i = 0; i < 4; ++i)
            #pragma unroll
            for (int j = 0; j < 4; ++j)
                acc[i][j] = __builtin_amdgcn_mfma_f32_16x16x32_bf16(
                    af[i], bfr[j], acc[i][j], 0, 0, 0);
        __syncthreads();
    }

    int rg = lane >> 4;
    #pragma unroll
    for (int j = 0; j < 4; ++j) {
        int col = bcol + wn * 64 + j * 16 + rb;
        float bv = bias[col];
        float s = 0.f, s2 = 0.f;
        #pragma unroll
        for (int i = 0; i < 4; ++i) {
            #pragma unroll
            for (int q = 0; q < 4; ++q) {
                int row = brow + wm * 64 + i * 16 + rg * 4 + q;
                float o = acc[i][j][q] + bv;
                unsigned short hb = f2bf(o);
                if (row < N_NODES) {
                    H[(size_t)row * DIM + col] = hb;
                    float of = bf2f(hb);
                    s += of;
                    s2 = fmaf(of, of, s2);
                }
            }
        }
        // reduce across the 4 row-groups (lanes rb, rb+16, rb+32, rb+48)
        s  += __shfl_xor(s, 16);
        s  += __shfl_xor(s, 32);
        s2 += __shfl_xor(s2, 16);
        s2 += __shfl_xor(s2, 32);
        if (rg == 0) {
            atomicAdd(&ssum[col], s);
            atomicAdd(&ssq[col], s2);
        }
    }
}

// ---------------- BN finalize + normalize ----------------------------------

__global__ void k_finalize(const float* __restrict__ ssum, const float* __restrict__ ssq,
                           const float* __restrict__ gamma, const float* __restrict__ beta,
                           float* __restrict__ scale, float* __restrict__ shift) {
    int c = threadIdx.x;
    float mu  = ssum[c] * (1.0f / N_NODES);
    float var = ssq[c] * (1.0f / N_NODES) - mu * mu;
    float rstd = rsqrtf(var + BN_EPS);
    float sc = rstd * gamma[c];
    scale[c] = sc;
    shift[c] = beta[c] - mu * sc;
}

// last=0: write bf16 x into Acat cols 256..511. last=1: fp32 to outF.
__global__ void k_norm_relu(const unsigned short* __restrict__ H,
                            const float* __restrict__ scale,
                            const float* __restrict__ shift, float* __restrict__ outF,
                            unsigned short* __restrict__ Acat, int last) {
    __shared__ float sc[DIM], sh[DIM];
    sc[threadIdx.x] = scale[threadIdx.x];
    sh[threadIdx.x] = shift[threadIdx.x];
    __syncthreads();
    size_t total8 = (size_t)N_NODES * DIM / 8;   // uint4 = 8 bf16
    for (size_t i = (size_t)blockIdx.x * blockDim.x + threadIdx.x; i < total8;
         i += (size_t)gridDim.x * blockDim.x) {
        uint4 raw = ((const uint4*)H)[i];
        int node = (int)(i >> 5);            // DIM/8 = 32 vectors per row
        int c = ((int)i & 31) * 8;
        unsigned int w[4] = {raw.x, raw.y, raw.z, raw.w};
        float o[8];
        #pragma unroll
        for (int q = 0; q < 4; ++q) {
            float lo = bf2f((unsigned short)(w[q] & 0xFFFF));
            float hi = bf2f((unsigned short)(w[q] >> 16));
            o[q * 2 + 0] = fmaxf(fmaf(lo, sc[c + q * 2 + 0], sh[c + q * 2 + 0]), 0.f);
            o[q * 2 + 1] = fmaxf(fmaf(hi, sc[c + q * 2 + 1], sh[c + q * 2 + 1]), 0.f);
        }
        if (last) {
            float4 f0 = make_float4(o[0], o[1], o[2], o[3]);
            float4 f1 = make_float4(o[4], o[5], o[6], o[7]);
            *(float4*)(outF + (size_t)node * DIM + c)     = f0;
            *(float4*)(outF + (size_t)node * DIM + c + 4) = f1;
        } else {
            uint4 u;
            unsigned int uw[4];
            #pragma unroll
            for (int q = 0; q < 4; ++q)
                uw[q] = (unsigned int)f2bf(o[q * 2 + 0]) |
                        ((unsigned int)f2bf(o[q * 2 + 1]) << 16);
            u.x = uw[0]; u.y = uw[1]; u.z = uw[2]; u.w = uw[3];
            *(uint4*)&Acat[(size_t)node * KDIM + DIM + c] = u;
        }
    }
}

// ---------------- launch ----------------------------------------------------

extern "C" void kernel_launch(void* const* d_in, const int* in_sizes, int n_in,
                              void* d_out, int out_size, void* d_ws, size_t ws_size,
                              hipStream_t stream) {
    const float* x0    = (const float*)d_in[0];
    const float* Wl    = (const float*)d_in[1];
    const float* bl    = (const float*)d_in[2];
    const float* Wr    = (const float*)d_in[3];
    const float* gamma = (const float*)d_in[4];
    const float* beta  = (const float*)d_in[5];
    const int*   ei    = (const int*)d_in[6];
    const int* e_src = ei;
    const int* e_dst = ei + N_EDGES;

    char* ws = (char*)d_ws;
    size_t off = 0;
    auto alloc = [&](size_t bytes) { char* p = ws + off; off = (off + bytes + 255) & ~(size_t)255; return p; };
    unsigned short* Acat = (unsigned short*)alloc((size_t)N_PAD * KDIM * 2);  // 51.4 MB
    unsigned short* Hbuf = (unsigned short*)alloc((size_t)N_PAD * DIM * 2);   // 25.7 MB
    unsigned short* Wcat = (unsigned short*)alloc((size_t)3 * DIM * KDIM * 2);
    int*   csr_src = (int*)alloc((size_t)N_EDGES * 4);
    int*   csr_off = (int*)alloc((size_t)(N_NODES + 1) * 4);
    int*   degi    = (int*)alloc((size_t)N_NODES * 4);
    int*   cursor  = (int*)alloc((size_t)N_NODES * 4);
    int*   bsums   = (int*)alloc((size_t)SCAN_NB * 4);
    float* inv_deg = (float*)alloc((size_t)N_NODES * 4);
    float* ssum    = (float*)alloc(DIM * 4 * 2);
    float* ssq     = ssum + DIM;
    float* scale   = (float*)alloc(DIM * 4);
    float* shift   = (float*)alloc(DIM * 4);

    hipMemsetAsync(degi, 0, (size_t)N_NODES * 4, stream);
    hipMemsetAsync(cursor, 0, (size_t)N_NODES * 4, stream);

    int eb = (N_EDGES + 255) / 256;
    k_deg_count<<<eb, 256, 0, stream>>>(e_dst, degi);
    k_scan1<<<SCAN_NB, 1024, 0, stream>>>(degi, csr_off, inv_deg, bsums);
    k_scan2<<<1, 64, 0, stream>>>(bsums);
    k_scan3<<<SCAN_NB, 1024, 0, stream>>>(csr_off, bsums);
    k_fill<<<eb, 256, 0, stream>>>(e_src, e_dst, csr_off, cursor, csr_src);
    k_prep_w<<<(3 * DIM * KDIM + 255) / 256, 256, 0, stream>>>(Wl, Wr, Wcat);
    k_x2bf<<<(N_NODES * (DIM / 4) + 255) / 256, 256, 0, stream>>>(x0, Acat);

    for (int l = 0; l < 3; ++l) {
        k_aggregate<<<(N_NODES + 3) / 4, 256, 0, stream>>>(Acat, csr_off, csr_src, inv_deg, Acat);
        hipMemsetAsync(ssum, 0, DIM * 4 * 2, stream);
        k_gemm_mfma<<<dim3((N_NODES + 127) / 128, DIM / 128), 256, 0, stream>>>(
            Acat, Wcat + (size_t)l * DIM * KDIM, bl + (size_t)l * DIM, Hbuf, ssum, ssq);
        k_finalize<<<1, 256, 0, stream>>>(ssum, ssq, gamma + (size_t)l * DIM,
                                          beta + (size_t)l * DIM, scale, shift);
        k_norm_relu<<<2048, 256, 0, stream>>>(Hbuf, scale, shift, (float*)d_out,
                                              Acat, (l == 2) ? 1 : 0);
    }
}

// Round 6
// 578.145 us; speedup vs baseline: 2.3862x; 1.1893x over previous
//
#include <hip/hip_runtime.h>

#define N_NODES 50000
#define N_PAD   50176   // 392*128, covers GEMM tile over-read
#define N_EDGES 800000
#define DIM     256
#define KDIM    512     // concat [agg | x]
#define BN_EPS  1e-5f
#define SCAN_NB ((N_NODES + 1023) / 1024)   // 49

typedef __attribute__((ext_vector_type(8))) short short8;
typedef __attribute__((ext_vector_type(4))) float floatx4;

__device__ __forceinline__ float bf2f(unsigned short u) {
    return __uint_as_float(((unsigned int)u) << 16);
}
__device__ __forceinline__ unsigned short f2bf(float f) {
    unsigned int b = __float_as_uint(f);
    b = (b + 0x7FFF + ((b >> 16) & 1)) >> 16;   // RNE
    return (unsigned short)b;
}

__device__ __forceinline__ void gload_lds16(const void* g, void* l) {
    __builtin_amdgcn_global_load_lds(
        (const __attribute__((address_space(1))) unsigned int*)g,
        (__attribute__((address_space(3))) unsigned int*)l, 16, 0, 0);
}

// ---------------- CSR build (once per launch) -------------------------------

__global__ void k_deg_count(const int* __restrict__ dst, int* __restrict__ degi) {
    int e = blockIdx.x * blockDim.x + threadIdx.x;
    if (e < N_EDGES) atomicAdd(&degi[dst[e]], 1);
}

// Hierarchical scan: per-block inclusive scan + block sums.
__global__ void k_scan1(const int* __restrict__ degi, int* __restrict__ off,
                        float* __restrict__ inv_deg, int* __restrict__ bsums) {
    __shared__ int buf[1024];
    int i = blockIdx.x * 1024 + threadIdx.x;
    int v = (i < N_NODES) ? degi[i] : 0;
    if (i < N_NODES) inv_deg[i] = 1.0f / (float)max(v, 1);
    buf[threadIdx.x] = v;
    __syncthreads();
    for (int s = 1; s < 1024; s <<= 1) {
        int t = (threadIdx.x >= s) ? buf[threadIdx.x - s] : 0;
        __syncthreads();
        buf[threadIdx.x] += t;
        __syncthreads();
    }
    if (i < N_NODES) off[i + 1] = buf[threadIdx.x];   // local inclusive
    if (threadIdx.x == 1023) bsums[blockIdx.x] = buf[1023];
    if (i == 0) off[0] = 0;
}

// One wave scans the 49 block sums -> exclusive offsets, in place.
__global__ void k_scan2(int* __restrict__ bsums) {
    int t = threadIdx.x;   // 64 threads
    int orig = (t < SCAN_NB) ? bsums[t] : 0;
    int v = orig;
    for (int s = 1; s < 64; s <<= 1) {
        int u = __shfl_up(v, s, 64);
        if (t >= s) v += u;
    }
    if (t < SCAN_NB) bsums[t] = v - orig;   // exclusive
}

__global__ void k_scan3(int* __restrict__ off, const int* __restrict__ bsums) {
    int i = blockIdx.x * 1024 + threadIdx.x;
    if (i < N_NODES) off[i + 1] += bsums[blockIdx.x];
}

__global__ void k_fill(const int* __restrict__ src, const int* __restrict__ dst,
                       const int* __restrict__ off, int* __restrict__ cursor,
                       int* __restrict__ csr_src) {
    int e = blockIdx.x * blockDim.x + threadIdx.x;
    if (e < N_EDGES) {
        int d = dst[e];
        int pos = atomicAdd(&cursor[d], 1);
        csr_src[off[d] + pos] = src[e];
    }
}

// ---------------- weight prep: Wcat_t[l][n][k] bf16 (transposed concat) -----

__global__ void k_prep_w(const float* __restrict__ Wl, const float* __restrict__ Wr,
                         unsigned short* __restrict__ Wcat) {
    int gid = blockIdx.x * blockDim.x + threadIdx.x;   // 3*256*512
    if (gid >= 3 * DIM * KDIM) return;
    int k = gid & (KDIM - 1);
    int n = (gid >> 9) & (DIM - 1);
    int l = gid >> 17;
    float v = (k < DIM) ? Wl[(size_t)l * DIM * DIM + (size_t)k * DIM + n]
                        : Wr[(size_t)l * DIM * DIM + (size_t)(k - DIM) * DIM + n];
    Wcat[gid] = f2bf(v);
}

// ---------------- x0 -> bf16 into Acat cols 256..511 ------------------------

__global__ void k_x2bf(const float* __restrict__ x, unsigned short* __restrict__ Acat) {
    size_t i = (size_t)blockIdx.x * blockDim.x + threadIdx.x;  // float4 units
    if (i >= (size_t)N_NODES * (DIM / 4)) return;
    int node = (int)(i >> 6);
    int c = ((int)i & 63) * 4;
    float4 v = ((const float4*)x)[i];
    ushort4 o; o.x = f2bf(v.x); o.y = f2bf(v.y); o.z = f2bf(v.z); o.w = f2bf(v.w);
    *(ushort4*)&Acat[(size_t)node * KDIM + DIM + c] = o;
}

// ---------------- mean aggregation: one node per HALF-wave, 16B/lane, x4 MLP

__device__ __forceinline__ void addv(float* a, uint4 v) {
    unsigned int w[4] = {v.x, v.y, v.z, v.w};
    #pragma unroll
    for (int q = 0; q < 4; ++q) {
        a[2 * q + 0] += bf2f((unsigned short)(w[q] & 0xFFFF));
        a[2 * q + 1] += bf2f((unsigned short)(w[q] >> 16));
    }
}

__global__ __launch_bounds__(256) void k_aggregate(
        const unsigned short* __restrict__ Acat_x,
        const int* __restrict__ off,
        const int* __restrict__ csr_src,
        const float* __restrict__ inv_deg,
        unsigned short* __restrict__ Acat_agg) {
    int gid = blockIdx.x * blockDim.x + threadIdx.x;
    int node = gid >> 5;               // one node per 32-lane group
    int lane = threadIdx.x & 31;       // 8 bf16 (16 B) per lane
    if (node >= N_NODES) return;
    int beg = off[node], end = off[node + 1];
    float a[8];
    #pragma unroll
    for (int q = 0; q < 8; ++q) a[q] = 0.f;
    const unsigned short* xb = Acat_x + DIM + lane * 8;   // x half of Acat row

    int e = beg;
    for (; e + 4 <= end; e += 4) {
        int s0 = csr_src[e + 0];
        int s1 = csr_src[e + 1];
        int s2 = csr_src[e + 2];
        int s3 = csr_src[e + 3];
        uint4 v0 = *(const uint4*)(xb + (size_t)s0 * KDIM);
        uint4 v1 = *(const uint4*)(xb + (size_t)s1 * KDIM);
        uint4 v2 = *(const uint4*)(xb + (size_t)s2 * KDIM);
        uint4 v3 = *(const uint4*)(xb + (size_t)s3 * KDIM);
        addv(a, v0); addv(a, v1); addv(a, v2); addv(a, v3);
    }
    for (; e < end; ++e) {
        uint4 v = *(const uint4*)(xb + (size_t)csr_src[e] * KDIM);
        addv(a, v);
    }

    float inv = inv_deg[node];
    unsigned int w[4];
    #pragma unroll
    for (int q = 0; q < 4; ++q)
        w[q] = (unsigned int)f2bf(a[2 * q] * inv) |
               ((unsigned int)f2bf(a[2 * q + 1] * inv) << 16);
    uint4 o; o.x = w[0]; o.y = w[1]; o.z = w[2]; o.w = w[3];
    *(uint4*)&Acat_agg[(size_t)node * KDIM + lane * 8] = o;
}

// ---------------- bf16 MFMA GEMM: H(bf16) = Acat @ Wcat_t^T + bias ----------
// Fused BN-stats: per-column sum/sumsq accumulated via shfl-reduce + atomics.

__global__ __launch_bounds__(256) void k_gemm_mfma(
        const unsigned short* __restrict__ A,
        const unsigned short* __restrict__ Bt,
        const float* __restrict__ bias, unsigned short* __restrict__ H,
        float* __restrict__ ssum, float* __restrict__ ssq) {
    __shared__ __align__(16) short Alds[128 * 32];   // 8 KB
    __shared__ __align__(16) short Blds[128 * 32];   // 8 KB
    int tid = threadIdx.x;
    int wid = tid >> 6;
    int lane = tid & 63;
    int wm = wid >> 1, wn = wid & 1;
    int brow = blockIdx.x * 128;
    int bcol = blockIdx.y * 128;

    floatx4 acc[4][4];
    #pragma unroll
    for (int i = 0; i < 4; ++i)
        #pragma unroll
        for (int j = 0; j < 4; ++j) acc[i][j] = (floatx4){0.f, 0.f, 0.f, 0.f};

    int st_r0 = (lane >> 2);          // row within 16-row chunk
    int st_s  = lane & 3;             // stored 16B slot
    int rb = lane & 15;               // frag row/col within 16
    int k16r = lane >> 4;             // frag k-slot (8 bf16)

    for (int kt = 0; kt < KDIM / 32; ++kt) {
        int k0 = kt * 32;
        #pragma unroll
        for (int q = 0; q < 2; ++q) {
            int c = wid * 2 + q;
            int r = c * 16 + st_r0;
            int k16 = (st_s - (r >> 1)) & 3;   // inverse swizzle on global source
            gload_lds16(A + (size_t)(brow + r) * KDIM + k0 + k16 * 8, &Alds[c * 512]);
            gload_lds16(Bt + (size_t)(bcol + r) * KDIM + k0 + k16 * 8, &Blds[c * 512]);
        }
        __syncthreads();

        short8 af[4], bfr[4];
        #pragma unroll
        for (int i = 0; i < 4; ++i) {
            int ra = wm * 64 + i * 16 + rb;
            int sa = (k16r + (ra >> 1)) & 3;
            af[i] = *(const short8*)&Alds[ra * 32 + sa * 8];
            int rc = wn * 64 + i * 16 + rb;
            int sc = (k16r + (rc >> 1)) & 3;
            bfr[i] = *(const short8*)&Blds[rc * 32 + sc * 8];
        }
        #pragma unroll
        for (int i = 0; i < 4; ++i)
            #pragma unroll
            for (int j = 0; j < 4; ++j)
                acc[i][j] = __builtin_amdgcn_mfma_f32_16x16x32_bf16(
                    af[i], bfr[j], acc[i][j], 0, 0, 0);
        __syncthreads();
    }

    int rg = lane >> 4;
    #pragma unroll
    for (int j = 0; j < 4; ++j) {
        int col = bcol + wn * 64 + j * 16 + rb;
        float bv = bias[col];
        float s = 0.f, s2 = 0.f;
        #pragma unroll
        for (int i = 0; i < 4; ++i) {
            #pragma unroll
            for (int q = 0; q < 4; ++q) {
                int row = brow + wm * 64 + i * 16 + rg * 4 + q;
                float o = acc[i][j][q] + bv;
                unsigned short hb = f2bf(o);
                if (row < N_NODES) {
                    H[(size_t)row * DIM + col] = hb;
                    float of = bf2f(hb);
                    s += of;
                    s2 = fmaf(of, of, s2);
                }
            }
        }
        s  += __shfl_xor(s, 16);
        s  += __shfl_xor(s, 32);
        s2 += __shfl_xor(s2, 16);
        s2 += __shfl_xor(s2, 32);
        if (rg == 0) {
            atomicAdd(&ssum[col], s);
            atomicAdd(&ssq[col], s2);
        }
    }
}

// ---------------- normalize (+fused BN finalize per block) ------------------
// last=0: write bf16 x into Acat cols 256..511. last=1: fp32 to outF.

__global__ void k_norm_relu(const unsigned short* __restrict__ H,
                            const float* __restrict__ ssum,
                            const float* __restrict__ ssq,
                            const float* __restrict__ gamma,
                            const float* __restrict__ beta,
                            float* __restrict__ outF,
                            unsigned short* __restrict__ Acat, int last) {
    __shared__ float sc[DIM], sh[DIM];
    {
        int c = threadIdx.x;
        float mu  = ssum[c] * (1.0f / N_NODES);
        float var = ssq[c] * (1.0f / N_NODES) - mu * mu;
        float rstd = rsqrtf(var + BN_EPS);
        float s = rstd * gamma[c];
        sc[c] = s;
        sh[c] = beta[c] - mu * s;
    }
    __syncthreads();
    size_t total8 = (size_t)N_NODES * DIM / 8;   // uint4 = 8 bf16
    for (size_t i = (size_t)blockIdx.x * blockDim.x + threadIdx.x; i < total8;
         i += (size_t)gridDim.x * blockDim.x) {
        uint4 raw = ((const uint4*)H)[i];
        int node = (int)(i >> 5);            // DIM/8 = 32 vectors per row
        int c = ((int)i & 31) * 8;
        unsigned int w[4] = {raw.x, raw.y, raw.z, raw.w};
        float o[8];
        #pragma unroll
        for (int q = 0; q < 4; ++q) {
            float lo = bf2f((unsigned short)(w[q] & 0xFFFF));
            float hi = bf2f((unsigned short)(w[q] >> 16));
            o[q * 2 + 0] = fmaxf(fmaf(lo, sc[c + q * 2 + 0], sh[c + q * 2 + 0]), 0.f);
            o[q * 2 + 1] = fmaxf(fmaf(hi, sc[c + q * 2 + 1], sh[c + q * 2 + 1]), 0.f);
        }
        if (last) {
            float4 f0 = make_float4(o[0], o[1], o[2], o[3]);
            float4 f1 = make_float4(o[4], o[5], o[6], o[7]);
            *(float4*)(outF + (size_t)node * DIM + c)     = f0;
            *(float4*)(outF + (size_t)node * DIM + c + 4) = f1;
        } else {
            uint4 u;
            unsigned int uw[4];
            #pragma unroll
            for (int q = 0; q < 4; ++q)
                uw[q] = (unsigned int)f2bf(o[q * 2 + 0]) |
                        ((unsigned int)f2bf(o[q * 2 + 1]) << 16);
            u.x = uw[0]; u.y = uw[1]; u.z = uw[2]; u.w = uw[3];
            *(uint4*)&Acat[(size_t)node * KDIM + DIM + c] = u;
        }
    }
}

// ---------------- launch ----------------------------------------------------

extern "C" void kernel_launch(void* const* d_in, const int* in_sizes, int n_in,
                              void* d_out, int out_size, void* d_ws, size_t ws_size,
                              hipStream_t stream) {
    const float* x0    = (const float*)d_in[0];
    const float* Wl    = (const float*)d_in[1];
    const float* bl    = (const float*)d_in[2];
    const float* Wr    = (const float*)d_in[3];
    const float* gamma = (const float*)d_in[4];
    const float* beta  = (const float*)d_in[5];
    const int*   ei    = (const int*)d_in[6];
    const int* e_src = ei;
    const int* e_dst = ei + N_EDGES;

    char* ws = (char*)d_ws;
    size_t off = 0;
    auto alloc = [&](size_t bytes) { char* p = ws + off; off = (off + bytes + 255) & ~(size_t)255; return p; };
    unsigned short* Acat = (unsigned short*)alloc((size_t)N_PAD * KDIM * 2);  // 51.4 MB
    unsigned short* Hbuf = (unsigned short*)alloc((size_t)N_PAD * DIM * 2);   // 25.7 MB
    unsigned short* Wcat = (unsigned short*)alloc((size_t)3 * DIM * KDIM * 2);
    int*   csr_src = (int*)alloc((size_t)N_EDGES * 4);
    int*   csr_off = (int*)alloc((size_t)(N_NODES + 1) * 4);
    int*   degi    = (int*)alloc((size_t)N_NODES * 4);
    int*   cursor  = (int*)alloc((size_t)N_NODES * 4);
    int*   bsums   = (int*)alloc((size_t)SCAN_NB * 4);
    float* inv_deg = (float*)alloc((size_t)N_NODES * 4);
    float* stats   = (float*)alloc((size_t)3 * 2 * DIM * 4);   // [layer][ssum|ssq][DIM]
    (void)ws_size;

    hipMemsetAsync(degi, 0, (size_t)N_NODES * 4, stream);
    hipMemsetAsync(cursor, 0, (size_t)N_NODES * 4, stream);
    hipMemsetAsync(stats, 0, (size_t)3 * 2 * DIM * 4, stream);

    int eb = (N_EDGES + 255) / 256;
    k_deg_count<<<eb, 256, 0, stream>>>(e_dst, degi);
    k_scan1<<<SCAN_NB, 1024, 0, stream>>>(degi, csr_off, inv_deg, bsums);
    k_scan2<<<1, 64, 0, stream>>>(bsums);
    k_scan3<<<SCAN_NB, 1024, 0, stream>>>(csr_off, bsums);
    k_fill<<<eb, 256, 0, stream>>>(e_src, e_dst, csr_off, cursor, csr_src);
    k_prep_w<<<(3 * DIM * KDIM + 255) / 256, 256, 0, stream>>>(Wl, Wr, Wcat);
    k_x2bf<<<(N_NODES * (DIM / 4) + 255) / 256, 256, 0, stream>>>(x0, Acat);

    for (int l = 0; l < 3; ++l) {
        float* ssum_l = stats + (size_t)l * 2 * DIM;
        float* ssq_l  = ssum_l + DIM;
        k_aggregate<<<(N_NODES * 32 + 255) / 256, 256, 0, stream>>>(
            Acat, csr_off, csr_src, inv_deg, Acat);
        k_gemm_mfma<<<dim3((N_NODES + 127) / 128, DIM / 128), 256, 0, stream>>>(
            Acat, Wcat + (size_t)l * DIM * KDIM, bl + (size_t)l * DIM, Hbuf, ssum_l, ssq_l);
        k_norm_relu<<<2048, 256, 0, stream>>>(Hbuf, ssum_l, ssq_l,
                                              gamma + (size_t)l * DIM, beta + (size_t)l * DIM,
                                              (float*)d_out, Acat, (l == 2) ? 1 : 0);
    }
}